// Round 3
// baseline (628.855 us; speedup 1.0000x reference)
//
#include <hip/hip_runtime.h>
#include <hip/hip_bf16.h>
#include <hip/hip_fp16.h>

#define N_NODES 100000
#define N_RADIAL 16
#define N_CONICAL 16
#define SCAN_BLK 1024
#define SCAN_NB  ((N_NODES + SCAN_BLK - 1) / SCAN_BLK)   // 98

// ---------------------------------------------------------------------------
// 1. Degree histogram: deg[v] = #occurrences of v anywhere in idx[0:2E]
//    (rows = concat(i,j) covers both halves). 3.2M int atomics.
// ---------------------------------------------------------------------------
__global__ __launch_bounds__(256) void count_kernel(
    const int* __restrict__ idx, int* __restrict__ cnt, int total) {
    int t = blockIdx.x * blockDim.x + threadIdx.x;
    if (t < total) atomicAdd(&cnt[idx[t]], 1);
}

// ---------------------------------------------------------------------------
// 2a. Per-block exclusive scan of cnt -> pos; block totals -> bsum.
// ---------------------------------------------------------------------------
__global__ __launch_bounds__(SCAN_BLK) void scan1_kernel(
    const int* __restrict__ cnt, int* __restrict__ pos, int* __restrict__ bsum) {
    __shared__ int s[SCAN_BLK];
    int t = threadIdx.x, i = blockIdx.x * SCAN_BLK + t;
    int v = (i < N_NODES) ? cnt[i] : 0;
    s[t] = v;
    for (int off = 1; off < SCAN_BLK; off <<= 1) {
        __syncthreads();
        int y = (t >= off) ? s[t - off] : 0;
        __syncthreads();
        s[t] += y;
    }
    if (i < N_NODES) pos[i] = s[t] - v;           // exclusive within block
    if (t == SCAN_BLK - 1) bsum[blockIdx.x] = s[t];
}

// 2b. Exclusive scan of the 98 block totals (single block).
__global__ __launch_bounds__(128) void scan2_kernel(int* __restrict__ bsum) {
    __shared__ int s[128];
    int t = threadIdx.x;
    int v = (t < SCAN_NB) ? bsum[t] : 0;
    s[t] = v;
    for (int off = 1; off < 128; off <<= 1) {
        __syncthreads();
        int y = (t >= off) ? s[t - off] : 0;
        __syncthreads();
        s[t] += y;
    }
    if (t < SCAN_NB) bsum[t] = s[t] - v;          // exclusive
}

// 2c. Add block prefix -> global exclusive offsets (in pos).
__global__ __launch_bounds__(SCAN_BLK) void scan3_kernel(
    int* __restrict__ pos, const int* __restrict__ bsum) {
    int i = blockIdx.x * SCAN_BLK + threadIdx.x;
    if (i < N_NODES) pos[i] += bsum[blockIdx.x];
}

// ---------------------------------------------------------------------------
// 3. CSR fill: nbr[pos[row]++] = col. Order within a row is irrelevant (sum).
//    After this kernel pos[row] == row_end (= start + cnt[row]).
// ---------------------------------------------------------------------------
__global__ __launch_bounds__(256) void fill_kernel(
    const int* __restrict__ idx, int* __restrict__ pos,
    int* __restrict__ nbr, int E) {
    int dir = blockIdx.x * blockDim.x + threadIdx.x;
    if (dir >= 2 * E) return;
    int row = idx[dir];
    int col = (dir < E) ? idx[dir + E] : idx[dir - E];
    int p = atomicAdd(&pos[row], 1);
    nbr[p] = col;
}

// ---------------------------------------------------------------------------
// 4. Gather-aggregate: 16 lanes per node (lane = channel). For each neighbor,
//    the 16 lanes read one coalesced 64B conical block of x (read-only, no
//    coherence traffic). f32 accumulate, divide by deg, ONE f16 round at the
//    end (vs round-2's chained f16 atomic accumulation).
// ---------------------------------------------------------------------------
__global__ __launch_bounds__(256) void gather_kernel(
    const float* __restrict__ x, const int* __restrict__ pos_end,
    const int* __restrict__ cnt, const int* __restrict__ nbr,
    __half* __restrict__ agg) {
    int t = blockIdx.x * blockDim.x + threadIdx.x;
    int n = t >> 4, ch = t & 15;
    if (n >= N_NODES) return;
    int c = cnt[n];
    int start = pos_end[n] - c;      // pos was advanced to row end by fill
    float a = 0.f;
    #pragma unroll 4
    for (int k = 0; k < c; k++) {
        int col = nbr[start + k];
        a += x[col * 32 + N_RADIAL + ch];
    }
    float d = (c < 1) ? 1.f : (float)c;
    agg[n * 16 + ch] = __float2half(a / d);
}

// ---------------------------------------------------------------------------
// 5. Per-node MLP: combined = [x[:,:16], agg] (32) -> 128 -> 32.
//    (256,1): VGPR cap 512 -> comb[32]+acc[32] stay in registers (round-1
//    profile showed VGPR_Count=44 -> scratch spill -> ~160us).
//    Weight indices are wave-uniform -> scalar loads on the free SMEM pipe.
// ---------------------------------------------------------------------------
__global__ __launch_bounds__(256, 1) void mlp_kernel(
    const float* __restrict__ x, const __half2* __restrict__ agg,
    const float* __restrict__ W1, const float* __restrict__ b1,
    const float* __restrict__ W2, const float* __restrict__ b2,
    float* __restrict__ out, int N) {
    int n = blockIdx.x * blockDim.x + threadIdx.x;
    if (n >= N) return;

    float comb[32];
    const float4* xr = (const float4*)(x + (size_t)n * 32);
    #pragma unroll
    for (int c = 0; c < 4; c++) {
        float4 v = xr[c];
        comb[c * 4 + 0] = v.x; comb[c * 4 + 1] = v.y;
        comb[c * 4 + 2] = v.z; comb[c * 4 + 3] = v.w;
    }
    const __half2* s2 = agg + (size_t)n * 8;
    #pragma unroll
    for (int c = 0; c < 8; c++) {
        float2 f = __half22float2(s2[c]);
        comb[N_RADIAL + 2 * c]     = f.x;
        comb[N_RADIAL + 2 * c + 1] = f.y;
    }

    float acc[32];
    #pragma unroll
    for (int o = 0; o < 32; o++) acc[o] = b2[o];

    #pragma unroll 4
    for (int k = 0; k < 128; k++) {
        float h = b1[k];
        #pragma unroll
        for (int c = 0; c < 32; c++) h = fmaf(comb[c], W1[c * 128 + k], h);
        h = fmaxf(h, 0.0f);
        #pragma unroll
        for (int o = 0; o < 32; o++) acc[o] = fmaf(h, W2[k * 32 + o], acc[o]);
    }

    float4* op = (float4*)(out + (size_t)n * 32);
    #pragma unroll
    for (int o = 0; o < 8; o++)
        op[o] = make_float4(acc[4 * o], acc[4 * o + 1], acc[4 * o + 2], acc[4 * o + 3]);
}

extern "C" void kernel_launch(void* const* d_in, const int* in_sizes, int n_in,
                              void* d_out, int out_size, void* d_ws, size_t ws_size,
                              hipStream_t stream) {
    const float* x   = (const float*)d_in[0];
    const int*   idx = (const int*)d_in[1];
    const float* W1  = (const float*)d_in[2];
    const float* b1  = (const float*)d_in[3];
    const float* W2  = (const float*)d_in[4];
    const float* b2  = (const float*)d_in[5];
    float* out = (float*)d_out;

    const int E = in_sizes[1] / 2;        // 1,600,000
    const int total = 2 * E;              // 3,200,000 edge-directions

    // ws layout (4.0 MB total; round 1 proved >=6.8 MB available):
    //   cnt[100000] i32 | pos[100000] i32 | bsum[1024] i32 | agg[100000*16] f16
    int*    cnt  = (int*)d_ws;
    int*    pos  = cnt + N_NODES;
    int*    bsum = pos + N_NODES;
    __half* agg  = (__half*)(bsum + 1024);
    // nbr (3.2M i32 = 12.8 MB) lives in d_out: dead until mlp_kernel, which
    // runs strictly after gather_kernel has consumed it (stream-ordered).
    int* nbr = (int*)d_out;

    hipMemsetAsync(cnt, 0, (size_t)N_NODES * sizeof(int), stream);

    count_kernel<<<(total + 255) / 256, 256, 0, stream>>>(idx, cnt, total);
    scan1_kernel<<<SCAN_NB, SCAN_BLK, 0, stream>>>(cnt, pos, bsum);
    scan2_kernel<<<1, 128, 0, stream>>>(bsum);
    scan3_kernel<<<SCAN_NB, SCAN_BLK, 0, stream>>>(pos, bsum);
    fill_kernel<<<(total + 255) / 256, 256, 0, stream>>>(idx, pos, nbr, E);
    gather_kernel<<<(N_NODES * 16 + 255) / 256, 256, 0, stream>>>(
        x, pos, cnt, nbr, agg);
    mlp_kernel<<<(N_NODES + 255) / 256, 256, 0, stream>>>(
        x, (const __half2*)agg, W1, b1, W2, b2, out, N_NODES);
}

// Round 4
// 500.851 us; speedup vs baseline: 1.2556x; 1.2556x over previous
//
#include <hip/hip_runtime.h>
#include <hip/hip_bf16.h>
#include <hip/hip_fp16.h>

#define N_NODES  100000
#define N_RADIAL 16
#define N_CONICAL 16

#define NPB    256                                   // nodes per bucket
#define NBKT   ((N_NODES + NPB - 1) / NPB)           // 391 buckets
#define NBLK_A 512                                   // binning blocks
#define HTOT   (NBKT * NBLK_A)                       // 200,192 hist entries
#define SCAN_BLK 1024
#define NB1    ((HTOT + SCAN_BLK - 1) / SCAN_BLK)    // 196

// ---------------------------------------------------------------------------
// A1. Per-block bucket histogram. Block b scans its chunk of directions,
//     counts rows per bucket in LDS, writes hist[bucket*NBLK_A + b].
// ---------------------------------------------------------------------------
__global__ __launch_bounds__(256) void hist_kernel(
    const int* __restrict__ idx, int* __restrict__ hist,
    int chunk, int total) {
    __shared__ int lh[NBKT];
    int b = blockIdx.x, tid = threadIdx.x;
    for (int i = tid; i < NBKT; i += 256) lh[i] = 0;
    __syncthreads();
    int lo = b * chunk;
    int hi = min(lo + chunk, total);
    for (int d = lo + tid; d < hi; d += 256)
        atomicAdd(&lh[idx[d] >> 8], 1);
    __syncthreads();
    for (int i = tid; i < NBKT; i += 256)
        hist[i * NBLK_A + b] = lh[i];
}

// ---------------------------------------------------------------------------
// A2. 3-kernel exclusive scan over hist (HTOT entries) -> hoff.
// ---------------------------------------------------------------------------
__global__ __launch_bounds__(SCAN_BLK) void scan1_kernel(
    const int* __restrict__ in, int* __restrict__ out,
    int* __restrict__ bsum, int n) {
    __shared__ int s[SCAN_BLK];
    int t = threadIdx.x, i = blockIdx.x * SCAN_BLK + t;
    int v = (i < n) ? in[i] : 0;
    s[t] = v;
    for (int off = 1; off < SCAN_BLK; off <<= 1) {
        __syncthreads();
        int y = (t >= off) ? s[t - off] : 0;
        __syncthreads();
        s[t] += y;
    }
    if (i < n) out[i] = s[t] - v;
    if (t == SCAN_BLK - 1) bsum[blockIdx.x] = s[t];
}

__global__ __launch_bounds__(256) void scan2_kernel(int* __restrict__ bsum, int nb) {
    __shared__ int s[256];
    int t = threadIdx.x;
    int v = (t < nb) ? bsum[t] : 0;
    s[t] = v;
    for (int off = 1; off < 256; off <<= 1) {
        __syncthreads();
        int y = (t >= off) ? s[t - off] : 0;
        __syncthreads();
        s[t] += y;
    }
    if (t < nb) bsum[t] = s[t] - v;
}

__global__ __launch_bounds__(SCAN_BLK) void scan3_kernel(
    int* __restrict__ out, const int* __restrict__ bsum, int n) {
    int i = blockIdx.x * SCAN_BLK + threadIdx.x;
    if (i < n) out[i] += bsum[blockIdx.x];
}

// ---------------------------------------------------------------------------
// A3. Bin-scatter: same chunking as A1. LDS cursors seeded from hoff; each
//     direction's packed (row_local<<17 | col) goes to its bucket run.
//     Runs are block-private and short -> dirty L2 lines fill before
//     eviction -> WRITE_SIZE ~= 12.8 MB (vs 195 MB for the CSR fill).
// ---------------------------------------------------------------------------
__global__ __launch_bounds__(256) void bin_kernel(
    const int* __restrict__ idx, const int* __restrict__ hoff,
    unsigned int* __restrict__ binned, int chunk, int total, int E) {
    __shared__ int cur[NBKT];
    int b = blockIdx.x, tid = threadIdx.x;
    for (int i = tid; i < NBKT; i += 256)
        cur[i] = hoff[i * NBLK_A + b];
    __syncthreads();
    int lo = b * chunk;
    int hi = min(lo + chunk, total);
    for (int d = lo + tid; d < hi; d += 256) {
        int row = idx[d];
        int col = (d < E) ? idx[d + E] : idx[d - E];
        int p = atomicAdd(&cur[row >> 8], 1);
        binned[p] = ((unsigned int)(row & 255) << 17) | (unsigned int)col;
    }
}

// ---------------------------------------------------------------------------
// B. Bucket accumulate: one block per bucket. LDS f32 accumulator
//    (256 nodes x 16 ch, stride 17 to spread banks) + LDS degree counts.
//    Zero device-scope fp atomics; gather of x is read-only L2/L3 traffic.
//    Output: agg[n][ch] = sum/max(deg,1) rounded once to f16.
// ---------------------------------------------------------------------------
__global__ __launch_bounds__(256) void agg_kernel(
    const float* __restrict__ x, const int* __restrict__ hoff,
    const unsigned int* __restrict__ binned, __half* __restrict__ agg,
    int total) {
    __shared__ float sacc[NPB * 17];
    __shared__ int   sdc[NPB];
    int b = blockIdx.x, tid = threadIdx.x;
    for (int i = tid; i < NPB * 17; i += 256) sacc[i] = 0.f;
    if (tid < NPB) sdc[tid] = 0;
    __syncthreads();

    int start = hoff[b * NBLK_A];
    int end   = (b == NBKT - 1) ? total : hoff[(b + 1) * NBLK_A];

    #pragma unroll 2
    for (int e = start + tid; e < end; e += 256) {
        unsigned int p = binned[e];
        int col = (int)(p & 0x1FFFFu);
        int rl  = (int)(p >> 17);
        const float4* xp = (const float4*)(x + (size_t)col * 32 + N_RADIAL);
        float4 v0 = xp[0], v1 = xp[1], v2 = xp[2], v3 = xp[3];
        float* a = &sacc[rl * 17];
        atomicAdd(&a[0],  v0.x); atomicAdd(&a[1],  v0.y);
        atomicAdd(&a[2],  v0.z); atomicAdd(&a[3],  v0.w);
        atomicAdd(&a[4],  v1.x); atomicAdd(&a[5],  v1.y);
        atomicAdd(&a[6],  v1.z); atomicAdd(&a[7],  v1.w);
        atomicAdd(&a[8],  v2.x); atomicAdd(&a[9],  v2.y);
        atomicAdd(&a[10], v2.z); atomicAdd(&a[11], v2.w);
        atomicAdd(&a[12], v3.x); atomicAdd(&a[13], v3.y);
        atomicAdd(&a[14], v3.z); atomicAdd(&a[15], v3.w);
        atomicAdd(&sdc[rl], 1);
    }
    __syncthreads();

    int n = b * NPB + tid;
    if (n < N_NODES) {
        int c = sdc[tid];
        float inv = 1.0f / (float)max(c, 1);
        __half2* ap = (__half2*)(agg + (size_t)n * 16);
        #pragma unroll
        for (int h = 0; h < 8; h++) {
            float lo = sacc[tid * 17 + 2 * h]     * inv;
            float hi2 = sacc[tid * 17 + 2 * h + 1] * inv;
            ap[h] = __floats2half2_rn(lo, hi2);
        }
    }
}

// ---------------------------------------------------------------------------
// C. MLP: combined = [x[:,:16], agg] (32) -> relu(·W1+b1) (128) -> ·W2+b2 (32).
//    Weights staged in LDS (W1 transposed so inner reads are contiguous
//    float4 broadcasts). comb[32]+acc[32] in VGPRs; (256,2) caps at 256 VGPR.
// ---------------------------------------------------------------------------
__global__ __launch_bounds__(256, 2) void mlp_kernel(
    const float* __restrict__ x, const __half* __restrict__ agg,
    const float* __restrict__ W1, const float* __restrict__ b1,
    const float* __restrict__ W2, const float* __restrict__ b2,
    float* __restrict__ out, int N) {
    __shared__ float sW1t[128 * 32];   // [k][c]
    __shared__ float sW2 [128 * 32];   // [k][o]
    __shared__ float sB1[128];
    __shared__ float sB2[32];
    int tid = threadIdx.x;
    for (int i = tid; i < 4096; i += 256) {
        int c = i >> 7, k = i & 127;
        sW1t[k * 32 + c] = W1[i];      // transpose W1 (32x128 -> [k][c])
        sW2[i] = W2[i];                // W2 already [k][o]
    }
    if (tid < 128) sB1[tid] = b1[tid];
    if (tid < 32)  sB2[tid] = b2[tid];
    __syncthreads();

    int n = blockIdx.x * 256 + tid;
    if (n >= N) return;

    float comb[32];
    const float4* xr = (const float4*)(x + (size_t)n * 32);
    #pragma unroll
    for (int c = 0; c < 4; c++) {
        float4 v = xr[c];
        comb[c * 4 + 0] = v.x; comb[c * 4 + 1] = v.y;
        comb[c * 4 + 2] = v.z; comb[c * 4 + 3] = v.w;
    }
    const __half2* ar = (const __half2*)(agg + (size_t)n * 16);
    #pragma unroll
    for (int c = 0; c < 8; c++) {
        float2 f = __half22float2(ar[c]);
        comb[N_RADIAL + 2 * c]     = f.x;
        comb[N_RADIAL + 2 * c + 1] = f.y;
    }

    float acc[32];
    #pragma unroll
    for (int o = 0; o < 32; o++) acc[o] = sB2[o];

    #pragma unroll 2
    for (int k = 0; k < 128; k++) {
        const float4* w1 = (const float4*)&sW1t[k * 32];
        float h = sB1[k];
        #pragma unroll
        for (int q = 0; q < 8; q++) {
            float4 w = w1[q];
            h = fmaf(comb[4 * q + 0], w.x, h);
            h = fmaf(comb[4 * q + 1], w.y, h);
            h = fmaf(comb[4 * q + 2], w.z, h);
            h = fmaf(comb[4 * q + 3], w.w, h);
        }
        h = fmaxf(h, 0.0f);
        const float4* w2 = (const float4*)&sW2[k * 32];
        #pragma unroll
        for (int q = 0; q < 8; q++) {
            float4 w = w2[q];
            acc[4 * q + 0] = fmaf(h, w.x, acc[4 * q + 0]);
            acc[4 * q + 1] = fmaf(h, w.y, acc[4 * q + 1]);
            acc[4 * q + 2] = fmaf(h, w.z, acc[4 * q + 2]);
            acc[4 * q + 3] = fmaf(h, w.w, acc[4 * q + 3]);
        }
    }

    float4* op = (float4*)(out + (size_t)n * 32);
    #pragma unroll
    for (int o = 0; o < 8; o++)
        op[o] = make_float4(acc[4 * o], acc[4 * o + 1], acc[4 * o + 2], acc[4 * o + 3]);
}

extern "C" void kernel_launch(void* const* d_in, const int* in_sizes, int n_in,
                              void* d_out, int out_size, void* d_ws, size_t ws_size,
                              hipStream_t stream) {
    const float* x   = (const float*)d_in[0];
    const int*   idx = (const int*)d_in[1];
    const float* W1  = (const float*)d_in[2];
    const float* b1  = (const float*)d_in[3];
    const float* W2  = (const float*)d_in[4];
    const float* b2  = (const float*)d_in[5];
    float* out = (float*)d_out;

    const int E = in_sizes[1] / 2;     // 1,600,000
    const int total = 2 * E;           // 3,200,000
    const int chunk = (total + NBLK_A - 1) / NBLK_A;   // 6250

    // ws layout (~4.6 MB; round 1 proved >= 6.8 MB usable):
    //   hist[HTOT] | hoff[HTOT] | bsum[256] | agg[100096*16] f16
    int*    hist = (int*)d_ws;
    int*    hoff = hist + HTOT;
    int*    bsum = hoff + HTOT;
    __half* agg  = (__half*)(bsum + 256);
    // binned (3.2M u32 = 12.8 MB) lives in d_out: dead until mlp writes it,
    // and mlp runs strictly after agg consumed it (stream-ordered).
    unsigned int* binned = (unsigned int*)d_out;

    hist_kernel<<<NBLK_A, 256, 0, stream>>>(idx, hist, chunk, total);
    scan1_kernel<<<NB1, SCAN_BLK, 0, stream>>>(hist, hoff, bsum, HTOT);
    scan2_kernel<<<1, 256, 0, stream>>>(bsum, NB1);
    scan3_kernel<<<NB1, SCAN_BLK, 0, stream>>>(hoff, bsum, HTOT);
    bin_kernel<<<NBLK_A, 256, 0, stream>>>(idx, hoff, binned, chunk, total, E);
    agg_kernel<<<NBKT, 256, 0, stream>>>(x, hoff, binned, agg, total);
    mlp_kernel<<<(N_NODES + 255) / 256, 256, 0, stream>>>(
        x, agg, W1, b1, W2, b2, out, N_NODES);
}

// Round 5
// 498.589 us; speedup vs baseline: 1.2613x; 1.0045x over previous
//
#include <hip/hip_runtime.h>
#include <hip/hip_bf16.h>
#include <hip/hip_fp16.h>

#define N_NODES  100000
#define N_RADIAL 16
#define N_CONICAL 16

#define NPB    128                                   // nodes per bucket
#define NBKT   ((N_NODES + NPB - 1) / NPB)           // 782 buckets
#define NBLK_A 256                                   // binning blocks
#define BTHR   512                                   // binning block threads
#define HTOT   (NBKT * NBLK_A)                       // 200,192 hist entries
#define SCAN_BLK 1024
#define NB1    ((HTOT + SCAN_BLK - 1) / SCAN_BLK)    // 196

// ---------------------------------------------------------------------------
// A1. Per-block bucket histogram: block b counts rows per bucket (row>>7)
//     in its chunk of directions; hist[bucket*NBLK_A + b].
// ---------------------------------------------------------------------------
__global__ __launch_bounds__(BTHR) void hist_kernel(
    const int* __restrict__ idx, int* __restrict__ hist,
    int chunk, int total) {
    __shared__ int lh[NBKT];
    int b = blockIdx.x, tid = threadIdx.x;
    for (int i = tid; i < NBKT; i += BTHR) lh[i] = 0;
    __syncthreads();
    int lo = b * chunk;
    int hi = min(lo + chunk, total);
    for (int d = lo + tid; d < hi; d += BTHR)
        atomicAdd(&lh[idx[d] >> 7], 1);
    __syncthreads();
    for (int i = tid; i < NBKT; i += BTHR)
        hist[i * NBLK_A + b] = lh[i];
}

// ---------------------------------------------------------------------------
// A2. 3-kernel exclusive scan over hist (HTOT entries) -> hoff.
// ---------------------------------------------------------------------------
__global__ __launch_bounds__(SCAN_BLK) void scan1_kernel(
    const int* __restrict__ in, int* __restrict__ out,
    int* __restrict__ bsum, int n) {
    __shared__ int s[SCAN_BLK];
    int t = threadIdx.x, i = blockIdx.x * SCAN_BLK + t;
    int v = (i < n) ? in[i] : 0;
    s[t] = v;
    for (int off = 1; off < SCAN_BLK; off <<= 1) {
        __syncthreads();
        int y = (t >= off) ? s[t - off] : 0;
        __syncthreads();
        s[t] += y;
    }
    if (i < n) out[i] = s[t] - v;
    if (t == SCAN_BLK - 1) bsum[blockIdx.x] = s[t];
}

__global__ __launch_bounds__(256) void scan2_kernel(int* __restrict__ bsum, int nb) {
    __shared__ int s[256];
    int t = threadIdx.x;
    int v = (t < nb) ? bsum[t] : 0;
    s[t] = v;
    for (int off = 1; off < 256; off <<= 1) {
        __syncthreads();
        int y = (t >= off) ? s[t - off] : 0;
        __syncthreads();
        s[t] += y;
    }
    if (t < nb) bsum[t] = s[t] - v;
}

__global__ __launch_bounds__(SCAN_BLK) void scan3_kernel(
    int* __restrict__ out, const int* __restrict__ bsum, int n) {
    int i = blockIdx.x * SCAN_BLK + threadIdx.x;
    if (i < n) out[i] += bsum[blockIdx.x];
}

// ---------------------------------------------------------------------------
// A3. Bin-scatter: LDS cursors from hoff; packed (row_local<<17 | col).
//     Block-private sub-runs -> line-dense writes (R4 verified: WRITE_SIZE
//     collapsed vs the CSR fill).
// ---------------------------------------------------------------------------
__global__ __launch_bounds__(BTHR) void bin_kernel(
    const int* __restrict__ idx, const int* __restrict__ hoff,
    unsigned int* __restrict__ binned, int chunk, int total, int E) {
    __shared__ int cur[NBKT];
    int b = blockIdx.x, tid = threadIdx.x;
    for (int i = tid; i < NBKT; i += BTHR)
        cur[i] = hoff[i * NBLK_A + b];
    __syncthreads();
    int lo = b * chunk;
    int hi = min(lo + chunk, total);
    for (int d = lo + tid; d < hi; d += BTHR) {
        int row = idx[d];
        int col = (d < E) ? idx[d + E] : idx[d - E];
        int p = atomicAdd(&cur[row >> 7], 1);
        binned[p] = ((unsigned int)(row & 127) << 17) | (unsigned int)col;
    }
}

// ---------------------------------------------------------------------------
// B. Bucket accumulate. 1024 threads, 2 blocks/CU resident (32 waves/CU vs
//    R4's 4 -> latency hiding). 4 lanes per edge: lane q of a quad loads
//    float4 q of the 64B conical block (fully coalesced) and does only 4
//    ds_adds -> 4x shorter dependent chain, 256 edges in flight per block.
// ---------------------------------------------------------------------------
__global__ __launch_bounds__(1024, 2) void agg_kernel(
    const float* __restrict__ x, const int* __restrict__ hoff,
    const unsigned int* __restrict__ binned, __half* __restrict__ agg,
    int total) {
    __shared__ float sacc[NPB * 17];
    __shared__ int   sdc[NPB];
    int b = blockIdx.x, tid = threadIdx.x;
    for (int i = tid; i < NPB * 17; i += 1024) sacc[i] = 0.f;
    if (tid < NPB) sdc[tid] = 0;
    __syncthreads();

    int start = hoff[b * NBLK_A];
    int end   = (b == NBKT - 1) ? total : hoff[(b + 1) * NBLK_A];

    int q  = tid & 3;          // which float4 of the conical block
    int es = tid >> 2;         // edge slot 0..255

    for (int e = start + es; e < end; e += 256) {
        unsigned int p = binned[e];
        int col = (int)(p & 0x1FFFFu);
        int rl  = (int)(p >> 17);
        const float4* xp = (const float4*)(x + (size_t)col * 32 + N_RADIAL);
        float4 v = xp[q];
        float* a = &sacc[rl * 17 + q * 4];
        atomicAdd(&a[0], v.x); atomicAdd(&a[1], v.y);
        atomicAdd(&a[2], v.z); atomicAdd(&a[3], v.w);
        if (q == 0) atomicAdd(&sdc[rl], 1);
    }
    __syncthreads();

    // epilogue: 1024 threads = 128 nodes x 8 half2 lanes, coalesced 4KB store
    int nl = tid >> 3, h = tid & 7;
    int n = b * NPB + nl;
    if (n < N_NODES) {
        int c = sdc[nl];
        float inv = 1.0f / (float)max(c, 1);
        float lo  = sacc[nl * 17 + 2 * h]     * inv;
        float hi2 = sacc[nl * 17 + 2 * h + 1] * inv;
        ((__half2*)agg)[(size_t)n * 8 + h] = __floats2half2_rn(lo, hi2);
    }
}

// ---------------------------------------------------------------------------
// C. MLP: combined = [x[:,:16], agg] (32) -> relu(·W1+b1) (128) -> ·W2+b2.
//    Weights staged in LDS (W1 transposed -> contiguous float4 broadcasts).
// ---------------------------------------------------------------------------
__global__ __launch_bounds__(256, 2) void mlp_kernel(
    const float* __restrict__ x, const __half* __restrict__ agg,
    const float* __restrict__ W1, const float* __restrict__ b1,
    const float* __restrict__ W2, const float* __restrict__ b2,
    float* __restrict__ out, int N) {
    __shared__ float sW1t[128 * 32];   // [k][c]
    __shared__ float sW2 [128 * 32];   // [k][o]
    __shared__ float sB1[128];
    __shared__ float sB2[32];
    int tid = threadIdx.x;
    for (int i = tid; i < 4096; i += 256) {
        int c = i >> 7, k = i & 127;
        sW1t[k * 32 + c] = W1[i];
        sW2[i] = W2[i];
    }
    if (tid < 128) sB1[tid] = b1[tid];
    if (tid < 32)  sB2[tid] = b2[tid];
    __syncthreads();

    int n = blockIdx.x * 256 + tid;
    if (n >= N) return;

    float comb[32];
    const float4* xr = (const float4*)(x + (size_t)n * 32);
    #pragma unroll
    for (int c = 0; c < 4; c++) {
        float4 v = xr[c];
        comb[c * 4 + 0] = v.x; comb[c * 4 + 1] = v.y;
        comb[c * 4 + 2] = v.z; comb[c * 4 + 3] = v.w;
    }
    const __half2* ar = (const __half2*)(agg + (size_t)n * 16);
    #pragma unroll
    for (int c = 0; c < 8; c++) {
        float2 f = __half22float2(ar[c]);
        comb[N_RADIAL + 2 * c]     = f.x;
        comb[N_RADIAL + 2 * c + 1] = f.y;
    }

    float acc[32];
    #pragma unroll
    for (int o = 0; o < 32; o++) acc[o] = sB2[o];

    #pragma unroll 2
    for (int k = 0; k < 128; k++) {
        const float4* w1 = (const float4*)&sW1t[k * 32];
        float h = sB1[k];
        #pragma unroll
        for (int qq = 0; qq < 8; qq++) {
            float4 w = w1[qq];
            h = fmaf(comb[4 * qq + 0], w.x, h);
            h = fmaf(comb[4 * qq + 1], w.y, h);
            h = fmaf(comb[4 * qq + 2], w.z, h);
            h = fmaf(comb[4 * qq + 3], w.w, h);
        }
        h = fmaxf(h, 0.0f);
        const float4* w2 = (const float4*)&sW2[k * 32];
        #pragma unroll
        for (int qq = 0; qq < 8; qq++) {
            float4 w = w2[qq];
            acc[4 * qq + 0] = fmaf(h, w.x, acc[4 * qq + 0]);
            acc[4 * qq + 1] = fmaf(h, w.y, acc[4 * qq + 1]);
            acc[4 * qq + 2] = fmaf(h, w.z, acc[4 * qq + 2]);
            acc[4 * qq + 3] = fmaf(h, w.w, acc[4 * qq + 3]);
        }
    }

    float4* op = (float4*)(out + (size_t)n * 32);
    #pragma unroll
    for (int o = 0; o < 8; o++)
        op[o] = make_float4(acc[4 * o], acc[4 * o + 1], acc[4 * o + 2], acc[4 * o + 3]);
}

extern "C" void kernel_launch(void* const* d_in, const int* in_sizes, int n_in,
                              void* d_out, int out_size, void* d_ws, size_t ws_size,
                              hipStream_t stream) {
    const float* x   = (const float*)d_in[0];
    const int*   idx = (const int*)d_in[1];
    const float* W1  = (const float*)d_in[2];
    const float* b1  = (const float*)d_in[3];
    const float* W2  = (const float*)d_in[4];
    const float* b2  = (const float*)d_in[5];
    float* out = (float*)d_out;

    const int E = in_sizes[1] / 2;     // 1,600,000
    const int total = 2 * E;           // 3,200,000
    const int chunk = (total + NBLK_A - 1) / NBLK_A;   // 12,500

    // ws layout (~4.8 MB): hist[HTOT] | hoff[HTOT] | bsum[1024] | agg f16
    int*    hist = (int*)d_ws;
    int*    hoff = hist + HTOT;
    int*    bsum = hoff + HTOT;
    __half* agg  = (__half*)(bsum + 1024);
    // binned (3.2M u32 = 12.8 MB) lives in d_out: consumed by agg_kernel
    // strictly before mlp_kernel overwrites it (stream-ordered).
    unsigned int* binned = (unsigned int*)d_out;

    hist_kernel<<<NBLK_A, BTHR, 0, stream>>>(idx, hist, chunk, total);
    scan1_kernel<<<NB1, SCAN_BLK, 0, stream>>>(hist, hoff, bsum, HTOT);
    scan2_kernel<<<1, 256, 0, stream>>>(bsum, NB1);
    scan3_kernel<<<NB1, SCAN_BLK, 0, stream>>>(hoff, bsum, HTOT);
    bin_kernel<<<NBLK_A, BTHR, 0, stream>>>(idx, hoff, binned, chunk, total, E);
    agg_kernel<<<NBKT, 1024, 0, stream>>>(x, hoff, binned, agg, total);
    mlp_kernel<<<(N_NODES + 255) / 256, 256, 0, stream>>>(
        x, agg, W1, b1, W2, b2, out, N_NODES);
}

// Round 6
// 496.127 us; speedup vs baseline: 1.2675x; 1.0050x over previous
//
#include <hip/hip_runtime.h>
#include <hip/hip_bf16.h>
#include <hip/hip_fp16.h>

#define N_NODES  100000
#define N_RADIAL 16
#define N_CONICAL 16

#define NPB    256                                   // nodes per bucket
#define NBKT   ((N_NODES + NPB - 1) / NPB)           // 391 buckets
#define NBLK_A 256                                   // binning blocks
#define BTHR   512                                   // binning block threads
#define HTOT   (NBKT * NBLK_A)                       // 100,096 hist entries
#define SCAN_BLK 1024
#define NB1    ((HTOT + SCAN_BLK - 1) / SCAN_BLK)    // 98

// ---------------------------------------------------------------------------
// P. Pack conical half of x to f16: xcon[n][c] = (half)x[n][16+c].
//    3.2 MB result fits a single XCD's 4 MiB L2 -> edge gathers become
//    L2-resident (R4/R5 showed the wall = 148 MB of L2-miss line traffic
//    at ~450 GB/s).
// ---------------------------------------------------------------------------
__global__ __launch_bounds__(256) void pack_kernel(
    const float* __restrict__ x, __half2* __restrict__ xcon2) {
    int t = blockIdx.x * 256 + threadIdx.x;       // one half2 per thread
    if (t >= N_NODES * 8) return;
    int n = t >> 3, p = t & 7;
    const float2* xp = (const float2*)x;          // 16 float2 per node
    float2 v = xp[n * 16 + 8 + p];                // conical half
    xcon2[t] = __floats2half2_rn(v.x, v.y);
}

// ---------------------------------------------------------------------------
// A1. Per-block bucket histogram (bucket = row>>8): hist[bucket*NBLK_A + b].
// ---------------------------------------------------------------------------
__global__ __launch_bounds__(BTHR) void hist_kernel(
    const int* __restrict__ idx, int* __restrict__ hist,
    int chunk, int total) {
    __shared__ int lh[NBKT];
    int b = blockIdx.x, tid = threadIdx.x;
    for (int i = tid; i < NBKT; i += BTHR) lh[i] = 0;
    __syncthreads();
    int lo = b * chunk;
    int hi = min(lo + chunk, total);
    for (int d = lo + tid; d < hi; d += BTHR)
        atomicAdd(&lh[idx[d] >> 8], 1);
    __syncthreads();
    for (int i = tid; i < NBKT; i += BTHR)
        hist[i * NBLK_A + b] = lh[i];
}

// ---------------------------------------------------------------------------
// A2. 3-kernel exclusive scan over hist (HTOT entries) -> hoff.
// ---------------------------------------------------------------------------
__global__ __launch_bounds__(SCAN_BLK) void scan1_kernel(
    const int* __restrict__ in, int* __restrict__ out,
    int* __restrict__ bsum, int n) {
    __shared__ int s[SCAN_BLK];
    int t = threadIdx.x, i = blockIdx.x * SCAN_BLK + t;
    int v = (i < n) ? in[i] : 0;
    s[t] = v;
    for (int off = 1; off < SCAN_BLK; off <<= 1) {
        __syncthreads();
        int y = (t >= off) ? s[t - off] : 0;
        __syncthreads();
        s[t] += y;
    }
    if (i < n) out[i] = s[t] - v;
    if (t == SCAN_BLK - 1) bsum[blockIdx.x] = s[t];
}

__global__ __launch_bounds__(256) void scan2_kernel(int* __restrict__ bsum, int nb) {
    __shared__ int s[256];
    int t = threadIdx.x;
    int v = (t < nb) ? bsum[t] : 0;
    s[t] = v;
    for (int off = 1; off < 256; off <<= 1) {
        __syncthreads();
        int y = (t >= off) ? s[t - off] : 0;
        __syncthreads();
        s[t] += y;
    }
    if (t < nb) bsum[t] = s[t] - v;
}

__global__ __launch_bounds__(SCAN_BLK) void scan3_kernel(
    int* __restrict__ out, const int* __restrict__ bsum, int n) {
    int i = blockIdx.x * SCAN_BLK + threadIdx.x;
    if (i < n) out[i] += bsum[blockIdx.x];
}

// ---------------------------------------------------------------------------
// A3. Bin-scatter: LDS cursors from hoff; packed (row_local<<17 | col).
//     Block-private sub-runs -> line-dense writes (verified R4).
// ---------------------------------------------------------------------------
__global__ __launch_bounds__(BTHR) void bin_kernel(
    const int* __restrict__ idx, const int* __restrict__ hoff,
    unsigned int* __restrict__ binned, int chunk, int total, int E) {
    __shared__ int cur[NBKT];
    int b = blockIdx.x, tid = threadIdx.x;
    for (int i = tid; i < NBKT; i += BTHR)
        cur[i] = hoff[i * NBLK_A + b];
    __syncthreads();
    int lo = b * chunk;
    int hi = min(lo + chunk, total);
    for (int d = lo + tid; d < hi; d += BTHR) {
        int row = idx[d];
        int col = (d < E) ? idx[d + E] : idx[d - E];
        int p = atomicAdd(&cur[row >> 8], 1);
        binned[p] = ((unsigned int)(row & 255) << 17) | (unsigned int)col;
    }
}

// ---------------------------------------------------------------------------
// B. Bucket accumulate. 4 lanes/edge; lane q loads 8 B of f16 (channels
//    4q..4q+3) from the L2-resident xcon -> 32 B/edge gather (was 64) and
//    a 3.2 MB working set -> L2 hits after warmup. f32 LDS accumulation.
// ---------------------------------------------------------------------------
__global__ __launch_bounds__(1024, 2) void agg_kernel(
    const __half* __restrict__ xcon, const int* __restrict__ hoff,
    const unsigned int* __restrict__ binned, __half* __restrict__ agg,
    int total) {
    __shared__ float sacc[NPB * 17];
    __shared__ int   sdc[NPB];
    int b = blockIdx.x, tid = threadIdx.x;
    for (int i = tid; i < NPB * 17; i += 1024) sacc[i] = 0.f;
    for (int i = tid; i < NPB; i += 1024) sdc[i] = 0;
    __syncthreads();

    int start = hoff[b * NBLK_A];
    int end   = (b == NBKT - 1) ? total : hoff[(b + 1) * NBLK_A];

    int q  = tid & 3;          // which 8B/4-channel slice
    int es = tid >> 2;         // edge slot 0..255

    for (int e = start + es; e < end; e += 256) {
        unsigned int p = binned[e];
        int col = (int)(p & 0x1FFFFu);
        int rl  = (int)(p >> 17);
        const uint2* xp = (const uint2*)(xcon + (size_t)col * 16);
        uint2 raw = xp[q];
        float2 f0 = __half22float2(*(const __half2*)&raw.x);
        float2 f1 = __half22float2(*(const __half2*)&raw.y);
        float* a = &sacc[rl * 17 + q * 4];
        atomicAdd(&a[0], f0.x); atomicAdd(&a[1], f0.y);
        atomicAdd(&a[2], f1.x); atomicAdd(&a[3], f1.y);
        if (q == 0) atomicAdd(&sdc[rl], 1);
    }
    __syncthreads();

    // epilogue: 256 nodes x 8 half2 = 2048 slots over 1024 threads (2 iters)
    for (int i = tid; i < NPB * 8; i += 1024) {
        int nl = i >> 3, h = i & 7;
        int n = b * NPB + nl;
        if (n < N_NODES) {
            int c = sdc[nl];
            float inv = 1.0f / (float)max(c, 1);
            float lo  = sacc[nl * 17 + 2 * h]     * inv;
            float hi2 = sacc[nl * 17 + 2 * h + 1] * inv;
            ((__half2*)agg)[(size_t)n * 8 + h] = __floats2half2_rn(lo, hi2);
        }
    }
}

// ---------------------------------------------------------------------------
// C. MLP: combined = [x[:,:16], agg] (32) -> relu(·W1+b1) (128) -> ·W2+b2.
//    Weights staged in LDS (W1 transposed -> contiguous float4 broadcasts).
// ---------------------------------------------------------------------------
__global__ __launch_bounds__(256, 2) void mlp_kernel(
    const float* __restrict__ x, const __half* __restrict__ agg,
    const float* __restrict__ W1, const float* __restrict__ b1,
    const float* __restrict__ W2, const float* __restrict__ b2,
    float* __restrict__ out, int N) {
    __shared__ float sW1t[128 * 32];   // [k][c]
    __shared__ float sW2 [128 * 32];   // [k][o]
    __shared__ float sB1[128];
    __shared__ float sB2[32];
    int tid = threadIdx.x;
    for (int i = tid; i < 4096; i += 256) {
        int c = i >> 7, k = i & 127;
        sW1t[k * 32 + c] = W1[i];
        sW2[i] = W2[i];
    }
    if (tid < 128) sB1[tid] = b1[tid];
    if (tid < 32)  sB2[tid] = b2[tid];
    __syncthreads();

    int n = blockIdx.x * 256 + tid;
    if (n >= N) return;

    float comb[32];
    const float4* xr = (const float4*)(x + (size_t)n * 32);
    #pragma unroll
    for (int c = 0; c < 4; c++) {
        float4 v = xr[c];
        comb[c * 4 + 0] = v.x; comb[c * 4 + 1] = v.y;
        comb[c * 4 + 2] = v.z; comb[c * 4 + 3] = v.w;
    }
    const __half2* ar = (const __half2*)(agg + (size_t)n * 16);
    #pragma unroll
    for (int c = 0; c < 8; c++) {
        float2 f = __half22float2(ar[c]);
        comb[N_RADIAL + 2 * c]     = f.x;
        comb[N_RADIAL + 2 * c + 1] = f.y;
    }

    float acc[32];
    #pragma unroll
    for (int o = 0; o < 32; o++) acc[o] = sB2[o];

    #pragma unroll 2
    for (int k = 0; k < 128; k++) {
        const float4* w1 = (const float4*)&sW1t[k * 32];
        float h = sB1[k];
        #pragma unroll
        for (int qq = 0; qq < 8; qq++) {
            float4 w = w1[qq];
            h = fmaf(comb[4 * qq + 0], w.x, h);
            h = fmaf(comb[4 * qq + 1], w.y, h);
            h = fmaf(comb[4 * qq + 2], w.z, h);
            h = fmaf(comb[4 * qq + 3], w.w, h);
        }
        h = fmaxf(h, 0.0f);
        const float4* w2 = (const float4*)&sW2[k * 32];
        #pragma unroll
        for (int qq = 0; qq < 8; qq++) {
            float4 w = w2[qq];
            acc[4 * qq + 0] = fmaf(h, w.x, acc[4 * qq + 0]);
            acc[4 * qq + 1] = fmaf(h, w.y, acc[4 * qq + 1]);
            acc[4 * qq + 2] = fmaf(h, w.z, acc[4 * qq + 2]);
            acc[4 * qq + 3] = fmaf(h, w.w, acc[4 * qq + 3]);
        }
    }

    float4* op = (float4*)(out + (size_t)n * 32);
    #pragma unroll
    for (int o = 0; o < 8; o++)
        op[o] = make_float4(acc[4 * o], acc[4 * o + 1], acc[4 * o + 2], acc[4 * o + 3]);
}

extern "C" void kernel_launch(void* const* d_in, const int* in_sizes, int n_in,
                              void* d_out, int out_size, void* d_ws, size_t ws_size,
                              hipStream_t stream) {
    const float* x   = (const float*)d_in[0];
    const int*   idx = (const int*)d_in[1];
    const float* W1  = (const float*)d_in[2];
    const float* b1  = (const float*)d_in[3];
    const float* W2  = (const float*)d_in[4];
    const float* b2  = (const float*)d_in[5];
    float* out = (float*)d_out;

    const int E = in_sizes[1] / 2;     // 1,600,000
    const int total = 2 * E;           // 3,200,000
    const int chunk = (total + NBLK_A - 1) / NBLK_A;   // 12,500

    // ws layout, 6.81 MB (R1 proved >= 6.8 MB usable):
    //   region0 3.203 MB: hist[HTOT] (dead after scan1) -> agg f16 overlay
    //   hoff[HTOT] 400 KB | bsum 4 KB | xcon f16 3.2 MB
    char* base = (char*)d_ws;
    int*    hist = (int*)base;                         // region0 (early life)
    __half* agg  = (__half*)base;                      // region0 (late life)
    int*    hoff = (int*)(base + 3203072);
    int*    bsum = (int*)(base + 3203072 + 400384);
    __half* xcon = (__half*)(base + 3203072 + 400384 + 4096);
    // binned (3.2M u32 = 12.8 MB) lives in d_out: fully consumed by
    // agg_kernel strictly before mlp_kernel overwrites it (stream-ordered).
    unsigned int* binned = (unsigned int*)d_out;

    pack_kernel<<<(N_NODES * 8 + 255) / 256, 256, 0, stream>>>(
        x, (__half2*)xcon);
    hist_kernel<<<NBLK_A, BTHR, 0, stream>>>(idx, hist, chunk, total);
    scan1_kernel<<<NB1, SCAN_BLK, 0, stream>>>(hist, hoff, bsum, HTOT);
    scan2_kernel<<<1, 256, 0, stream>>>(bsum, NB1);
    scan3_kernel<<<NB1, SCAN_BLK, 0, stream>>>(hoff, bsum, HTOT);
    bin_kernel<<<NBLK_A, BTHR, 0, stream>>>(idx, hoff, binned, chunk, total, E);
    agg_kernel<<<NBKT, 1024, 0, stream>>>(xcon, hoff, binned, agg, total);
    mlp_kernel<<<(N_NODES + 255) / 256, 256, 0, stream>>>(
        x, agg, W1, b1, W2, b2, out, N_NODES);
}

// Round 7
// 180.992 us; speedup vs baseline: 3.4745x; 2.7411x over previous
//
#include <hip/hip_runtime.h>
#include <hip/hip_bf16.h>
#include <hip/hip_fp16.h>

#define N_NODES  100000
#define N_RADIAL 16
#define N_CONICAL 16

#define NPB    256                                   // nodes per bucket
#define NBKT   ((N_NODES + NPB - 1) / NPB)           // 391 buckets
#define NBLK_A 256                                   // binning blocks
#define BTHR   512                                   // binning block threads
#define HTOT   (NBKT * NBLK_A)                       // 100,096 hist entries
#define SCAN_BLK 1024
#define NB1    ((HTOT + SCAN_BLK - 1) / SCAN_BLK)    // 98
#define CAP    14336                                 // bucket edge capacity
                                                     // (mean 8184, sigma~90 -> 68-sigma margin)

// ---------------------------------------------------------------------------
// P. Pack conical half of x to f16 (3.2 MB -> per-XCD-L2-resident; verified
//    R6: FETCH 148->19.6 MB).
// ---------------------------------------------------------------------------
__global__ __launch_bounds__(256) void pack_kernel(
    const float* __restrict__ x, __half2* __restrict__ xcon2) {
    int t = blockIdx.x * 256 + threadIdx.x;
    if (t >= N_NODES * 8) return;
    int n = t >> 3, p = t & 7;
    const float2* xp = (const float2*)x;
    float2 v = xp[n * 16 + 8 + p];
    xcon2[t] = __floats2half2_rn(v.x, v.y);
}

// ---------------------------------------------------------------------------
// A1. Per-block bucket histogram (bucket = row>>8).
// ---------------------------------------------------------------------------
__global__ __launch_bounds__(BTHR) void hist_kernel(
    const int* __restrict__ idx, int* __restrict__ hist,
    int chunk, int total) {
    __shared__ int lh[NBKT];
    int b = blockIdx.x, tid = threadIdx.x;
    for (int i = tid; i < NBKT; i += BTHR) lh[i] = 0;
    __syncthreads();
    int lo = b * chunk;
    int hi = min(lo + chunk, total);
    for (int d = lo + tid; d < hi; d += BTHR)
        atomicAdd(&lh[idx[d] >> 8], 1);
    __syncthreads();
    for (int i = tid; i < NBKT; i += BTHR)
        hist[i * NBLK_A + b] = lh[i];
}

// ---------------------------------------------------------------------------
// A2. 3-kernel exclusive scan over hist -> hoff.
// ---------------------------------------------------------------------------
__global__ __launch_bounds__(SCAN_BLK) void scan1_kernel(
    const int* __restrict__ in, int* __restrict__ out,
    int* __restrict__ bsum, int n) {
    __shared__ int s[SCAN_BLK];
    int t = threadIdx.x, i = blockIdx.x * SCAN_BLK + t;
    int v = (i < n) ? in[i] : 0;
    s[t] = v;
    for (int off = 1; off < SCAN_BLK; off <<= 1) {
        __syncthreads();
        int y = (t >= off) ? s[t - off] : 0;
        __syncthreads();
        s[t] += y;
    }
    if (i < n) out[i] = s[t] - v;
    if (t == SCAN_BLK - 1) bsum[blockIdx.x] = s[t];
}

__global__ __launch_bounds__(256) void scan2_kernel(int* __restrict__ bsum, int nb) {
    __shared__ int s[256];
    int t = threadIdx.x;
    int v = (t < nb) ? bsum[t] : 0;
    s[t] = v;
    for (int off = 1; off < 256; off <<= 1) {
        __syncthreads();
        int y = (t >= off) ? s[t - off] : 0;
        __syncthreads();
        s[t] += y;
    }
    if (t < nb) bsum[t] = s[t] - v;
}

__global__ __launch_bounds__(SCAN_BLK) void scan3_kernel(
    int* __restrict__ out, const int* __restrict__ bsum, int n) {
    int i = blockIdx.x * SCAN_BLK + threadIdx.x;
    if (i < n) out[i] += bsum[blockIdx.x];
}

// ---------------------------------------------------------------------------
// A3. Bin-scatter: packed (row_local<<17 | col) grouped by bucket.
// ---------------------------------------------------------------------------
__global__ __launch_bounds__(BTHR) void bin_kernel(
    const int* __restrict__ idx, const int* __restrict__ hoff,
    unsigned int* __restrict__ binned, int chunk, int total, int E) {
    __shared__ int cur[NBKT];
    int b = blockIdx.x, tid = threadIdx.x;
    for (int i = tid; i < NBKT; i += BTHR)
        cur[i] = hoff[i * NBLK_A + b];
    __syncthreads();
    int lo = b * chunk;
    int hi = min(lo + chunk, total);
    for (int d = lo + tid; d < hi; d += BTHR) {
        int row = idx[d];
        int col = (d < E) ? idx[d + E] : idx[d - E];
        int p = atomicAdd(&cur[row >> 8], 1);
        binned[p] = ((unsigned int)(row & 255) << 17) | (unsigned int)col;
    }
}

// ---------------------------------------------------------------------------
// B. Bucket accumulate v2 — LDS-atomic diet.
//    R4/R5/R6 all measured ~342us regardless of memory behavior; the
//    invariant was 17 LDS lane-atomics/edge (~3.8 cyc/lane-atomic/CU).
//    v2: in-block counting sort by local node (2 atomics/edge), then
//    atomic-FREE register accumulation: quad per node, lane q owns
//    channels 4q..4q+3; node's edges are contiguous in sedge -> ds_read
//    broadcast + 8B L2-resident gather.
// ---------------------------------------------------------------------------
__global__ __launch_bounds__(1024, 2) void agg_kernel(
    const __half* __restrict__ xcon, const int* __restrict__ hoff,
    const unsigned int* __restrict__ binned, __half* __restrict__ agg,
    int total) {
    __shared__ unsigned int sedge[CAP];   // 56 KB
    __shared__ int scnt[NPB];
    __shared__ int soff[NPB];
    int b = blockIdx.x, tid = threadIdx.x;
    if (tid < NPB) scnt[tid] = 0;
    __syncthreads();

    int start = hoff[b * NBLK_A];
    int end   = (b == NBKT - 1) ? total : hoff[(b + 1) * NBLK_A];

    // pass 1: load edges (held in registers), count per local node
    unsigned int held[14];
    #pragma unroll
    for (int it = 0; it < 14; it++) {
        int e = start + tid + it * 1024;
        unsigned int p = 0xFFFFFFFFu;
        if (e < end) {
            p = binned[e];
            atomicAdd(&scnt[p >> 17], 1);
        }
        held[it] = p;
    }
    __syncthreads();

    // pass 2: exclusive scan of scnt -> soff (Hillis-Steele on 256 entries)
    if (tid < NPB) soff[tid] = scnt[tid];
    __syncthreads();
    for (int off = 1; off < NPB; off <<= 1) {
        int y = 0;
        if (tid < NPB && tid >= off) y = soff[tid - off];
        __syncthreads();
        if (tid < NPB) soff[tid] += y;
        __syncthreads();
    }
    if (tid < NPB) soff[tid] -= scnt[tid];     // inclusive -> exclusive
    __syncthreads();

    // pass 3: scatter cols into node-sorted order via LDS cursors
    #pragma unroll
    for (int it = 0; it < 14; it++) {
        unsigned int p = held[it];
        if (p != 0xFFFFFFFFu) {
            int pos = atomicAdd(&soff[p >> 17], 1);
            sedge[pos] = p & 0x1FFFFu;
        }
    }
    __syncthreads();

    // pass 4: atomic-free accumulate. quad per node, lane q -> ch 4q..4q+3.
    int nl = tid >> 2, q = tid & 3;
    int c  = scnt[nl];
    int s0 = soff[nl] - c;                     // soff advanced to row end
    float a0 = 0.f, a1 = 0.f, a2 = 0.f, a3 = 0.f;
    #pragma unroll 4
    for (int k = 0; k < c; k++) {
        int col = (int)sedge[s0 + k];          // broadcast within quad
        uint2 raw = ((const uint2*)(xcon + (size_t)col * 16))[q];
        float2 f0 = __half22float2(*(const __half2*)&raw.x);
        float2 f1 = __half22float2(*(const __half2*)&raw.y);
        a0 += f0.x; a1 += f0.y; a2 += f1.x; a3 += f1.y;
    }
    int n = b * NPB + nl;
    if (n < N_NODES) {
        float inv = 1.0f / (float)max(c, 1);
        __half2 h0 = __floats2half2_rn(a0 * inv, a1 * inv);
        __half2 h1 = __floats2half2_rn(a2 * inv, a3 * inv);
        uint2 st;
        st.x = *(unsigned int*)&h0;
        st.y = *(unsigned int*)&h1;
        *(uint2*)(agg + (size_t)n * 16 + q * 4) = st;   // coalesced 8B/lane
    }
}

// ---------------------------------------------------------------------------
// C. MLP, 2 nodes/thread (halves per-node ds_read_b128 traffic; grid = 196
//    blocks -> one block per CU, single round). (256,1): VGPR cap 512.
// ---------------------------------------------------------------------------
__global__ __launch_bounds__(256, 1) void mlp_kernel(
    const float* __restrict__ x, const __half* __restrict__ agg,
    const float* __restrict__ W1, const float* __restrict__ b1,
    const float* __restrict__ W2, const float* __restrict__ b2,
    float* __restrict__ out, int N) {
    __shared__ float sW1t[128 * 32];   // [k][c]
    __shared__ float sW2 [128 * 32];   // [k][o]
    __shared__ float sB1[128];
    __shared__ float sB2[32];
    int tid = threadIdx.x;
    for (int i = tid; i < 4096; i += 256) {
        int c = i >> 7, k = i & 127;
        sW1t[k * 32 + c] = W1[i];
        sW2[i] = W2[i];
    }
    if (tid < 128) sB1[tid] = b1[tid];
    if (tid < 32)  sB2[tid] = b2[tid];
    __syncthreads();

    int n0 = blockIdx.x * 512 + tid;
    int n1 = n0 + 256;
    bool v0 = n0 < N, v1 = n1 < N;

    float comb0[32], comb1[32];
    if (v0) {
        const float4* xr = (const float4*)(x + (size_t)n0 * 32);
        #pragma unroll
        for (int c = 0; c < 4; c++) {
            float4 v = xr[c];
            comb0[c*4+0] = v.x; comb0[c*4+1] = v.y;
            comb0[c*4+2] = v.z; comb0[c*4+3] = v.w;
        }
        const __half2* ar = (const __half2*)(agg + (size_t)n0 * 16);
        #pragma unroll
        for (int c = 0; c < 8; c++) {
            float2 f = __half22float2(ar[c]);
            comb0[16 + 2*c]     = f.x;
            comb0[16 + 2*c + 1] = f.y;
        }
    }
    if (v1) {
        const float4* xr = (const float4*)(x + (size_t)n1 * 32);
        #pragma unroll
        for (int c = 0; c < 4; c++) {
            float4 v = xr[c];
            comb1[c*4+0] = v.x; comb1[c*4+1] = v.y;
            comb1[c*4+2] = v.z; comb1[c*4+3] = v.w;
        }
        const __half2* ar = (const __half2*)(agg + (size_t)n1 * 16);
        #pragma unroll
        for (int c = 0; c < 8; c++) {
            float2 f = __half22float2(ar[c]);
            comb1[16 + 2*c]     = f.x;
            comb1[16 + 2*c + 1] = f.y;
        }
    }

    float acc0[32], acc1[32];
    #pragma unroll
    for (int o = 0; o < 32; o++) { acc0[o] = sB2[o]; acc1[o] = sB2[o]; }

    #pragma unroll 2
    for (int k = 0; k < 128; k++) {
        const float4* w1 = (const float4*)&sW1t[k * 32];
        float h0 = sB1[k], h1 = sB1[k];
        #pragma unroll
        for (int qq = 0; qq < 8; qq++) {
            float4 w = w1[qq];
            h0 = fmaf(comb0[4*qq+0], w.x, h0); h1 = fmaf(comb1[4*qq+0], w.x, h1);
            h0 = fmaf(comb0[4*qq+1], w.y, h0); h1 = fmaf(comb1[4*qq+1], w.y, h1);
            h0 = fmaf(comb0[4*qq+2], w.z, h0); h1 = fmaf(comb1[4*qq+2], w.z, h1);
            h0 = fmaf(comb0[4*qq+3], w.w, h0); h1 = fmaf(comb1[4*qq+3], w.w, h1);
        }
        h0 = fmaxf(h0, 0.0f); h1 = fmaxf(h1, 0.0f);
        const float4* w2 = (const float4*)&sW2[k * 32];
        #pragma unroll
        for (int qq = 0; qq < 8; qq++) {
            float4 w = w2[qq];
            acc0[4*qq+0] = fmaf(h0, w.x, acc0[4*qq+0]); acc1[4*qq+0] = fmaf(h1, w.x, acc1[4*qq+0]);
            acc0[4*qq+1] = fmaf(h0, w.y, acc0[4*qq+1]); acc1[4*qq+1] = fmaf(h1, w.y, acc1[4*qq+1]);
            acc0[4*qq+2] = fmaf(h0, w.z, acc0[4*qq+2]); acc1[4*qq+2] = fmaf(h1, w.z, acc1[4*qq+2]);
            acc0[4*qq+3] = fmaf(h0, w.w, acc0[4*qq+3]); acc1[4*qq+3] = fmaf(h1, w.w, acc1[4*qq+3]);
        }
    }

    if (v0) {
        float4* op = (float4*)(out + (size_t)n0 * 32);
        #pragma unroll
        for (int o = 0; o < 8; o++)
            op[o] = make_float4(acc0[4*o], acc0[4*o+1], acc0[4*o+2], acc0[4*o+3]);
    }
    if (v1) {
        float4* op = (float4*)(out + (size_t)n1 * 32);
        #pragma unroll
        for (int o = 0; o < 8; o++)
            op[o] = make_float4(acc1[4*o], acc1[4*o+1], acc1[4*o+2], acc1[4*o+3]);
    }
}

extern "C" void kernel_launch(void* const* d_in, const int* in_sizes, int n_in,
                              void* d_out, int out_size, void* d_ws, size_t ws_size,
                              hipStream_t stream) {
    const float* x   = (const float*)d_in[0];
    const int*   idx = (const int*)d_in[1];
    const float* W1  = (const float*)d_in[2];
    const float* b1  = (const float*)d_in[3];
    const float* W2  = (const float*)d_in[4];
    const float* b2  = (const float*)d_in[5];
    float* out = (float*)d_out;

    const int E = in_sizes[1] / 2;     // 1,600,000
    const int total = 2 * E;           // 3,200,000
    const int chunk = (total + NBLK_A - 1) / NBLK_A;   // 12,500

    // ws layout (6.81 MB, same as R6):
    //   region0 3.203 MB: hist (early) -> agg f16 (late)
    //   hoff 400 KB | bsum 4 KB | xcon f16 3.2 MB
    char* base = (char*)d_ws;
    int*    hist = (int*)base;
    __half* agg  = (__half*)base;
    int*    hoff = (int*)(base + 3203072);
    int*    bsum = (int*)(base + 3203072 + 400384);
    __half* xcon = (__half*)(base + 3203072 + 400384 + 4096);
    // binned (12.8 MB) in d_out: consumed by agg before mlp overwrites it.
    unsigned int* binned = (unsigned int*)d_out;

    pack_kernel<<<(N_NODES * 8 + 255) / 256, 256, 0, stream>>>(
        x, (__half2*)xcon);
    hist_kernel<<<NBLK_A, BTHR, 0, stream>>>(idx, hist, chunk, total);
    scan1_kernel<<<NB1, SCAN_BLK, 0, stream>>>(hist, hoff, bsum, HTOT);
    scan2_kernel<<<1, 256, 0, stream>>>(bsum, NB1);
    scan3_kernel<<<NB1, SCAN_BLK, 0, stream>>>(hoff, bsum, HTOT);
    bin_kernel<<<NBLK_A, BTHR, 0, stream>>>(idx, hoff, binned, chunk, total, E);
    agg_kernel<<<NBKT, 1024, 0, stream>>>(xcon, hoff, binned, agg, total);
    mlp_kernel<<<(N_NODES + 511) / 512, 256, 0, stream>>>(
        x, agg, W1, b1, W2, b2, out, N_NODES);
}